// Round 9
// baseline (7190.707 us; speedup 1.0000x reference)
//
#include <hip/hip_runtime.h>
#include <cstdint>
#include <cstddef>

#define BB 64      // batch
#define SS 50      // src len
#define TT 50      // tgt len
#define TD 49      // decoder steps
#define UU 1024    // hidden
#define EE 256     // embed
#define VT 16000   // tgt vocab
#define G3 3072    // 3*U
#define MPAD 3200  // 50*64 padded row count

using short8 = __attribute__((ext_vector_type(8))) short;
using short4v = __attribute__((ext_vector_type(4))) short;
using uint4v = __attribute__((ext_vector_type(4))) unsigned int;
using f32x4  = __attribute__((ext_vector_type(4))) float;

__device__ __forceinline__ short f2bf(float f) {
    uint32_t u = __float_as_uint(f);
    uint32_t r = (u + 0x7fffu + ((u >> 16) & 1u)) >> 16;
    return (short)r;
}
__device__ __forceinline__ float bf2f(short s) {
    return __uint_as_float(((uint32_t)(uint16_t)s) << 16);
}
__device__ __forceinline__ float sigm(float x) { return 1.0f / (1.0f + __expf(-x)); }
__device__ __forceinline__ float ftanh(float x) {
    float xc = fminf(fmaxf(x, -8.0f), 8.0f);
    float e = __expf(2.0f * xc);
    return (e - 1.0f) / (e + 1.0f);
}

// Cross-block protocol (encoder only): writes write-through (volatile 2B),
// reads plain cached on virgin (time-indexed) addresses. The decoder has NO
// cross-block traffic at all -- each block owns one batch row end-to-end.
__device__ __forceinline__ void vstore_bf(short* p, float v) { *(volatile short*)p = f2bf(v); }

// Leader-based grid barrier (encoder): per-block arrival flags, block 0
// ballot-polls 64 flags, releases via `go`.
__device__ __forceinline__ void gbar(int* flags, int* go, int t) {
    asm volatile("s_waitcnt vmcnt(0)" ::: "memory");   // my data stores drained
    __syncthreads();
    if (blockIdx.x == 0) {
        if (threadIdx.x < 64) {
            if (threadIdx.x == 0)
                __hip_atomic_store(&flags[0], t, __ATOMIC_RELAXED, __HIP_MEMORY_SCOPE_AGENT);
            int v;
            do {
                v = __hip_atomic_load(&flags[threadIdx.x], __ATOMIC_RELAXED, __HIP_MEMORY_SCOPE_AGENT);
            } while (__ballot(v >= t) != ~0ull);
            if (threadIdx.x == 0)
                __hip_atomic_store(go, t, __ATOMIC_RELAXED, __HIP_MEMORY_SCOPE_AGENT);
        }
    } else {
        if (threadIdx.x == 0) {
            __hip_atomic_store(&flags[blockIdx.x], t, __ATOMIC_RELAXED, __HIP_MEMORY_SCOPE_AGENT);
            while (__hip_atomic_load(go, __ATOMIC_RELAXED, __HIP_MEMORY_SCOPE_AGENT) < t)
                __builtin_amdgcn_s_sleep(1);
        }
    }
    __syncthreads();
    asm volatile("" ::: "memory");                     // no load hoisting above
}

typedef __attribute__((address_space(3))) void lds_vp;
typedef __attribute__((address_space(1))) void gl_vp;
__device__ __forceinline__ void gload16(void* lds, const void* g) {
    __builtin_amdgcn_global_load_lds((const gl_vp*)(uintptr_t)g,
                                     (lds_vp*)(uint32_t)(uintptr_t)lds,
                                     16, 0, 0);
}
__device__ __forceinline__ f32x4 mfma16(short8 a, short8 b, f32x4 c) {
    return __builtin_amdgcn_mfma_f32_16x16x32_bf16(a, b, c, 0, 0, 0);
}

// ---------------------------------------------------------------------------
// bf16 MFMA GEMM: C[m][n] = sum_k A[m][k]*Bt[n][k] (+bias)
// REMAP 0: row-major [M][N].
// REMAP 1: rows m=s*64+b remapped to [b][s][N]   (keys layout)
// REMAP 2: [b][s][u][gate-pad4]                  (P layout, N=3072)
// ---------------------------------------------------------------------------
template<int BM, int BN, int WM, int WN, bool OUT_BF16, int REMAP>
__global__ __launch_bounds__(256) void gemm_bf16(
    const short* __restrict__ A, const short* __restrict__ Bt,
    const float* __restrict__ bias, void* __restrict__ C, int N, int K,
    int lda, int ldb)
{
    constexpr int BK = 32;
    __shared__ __attribute__((aligned(16))) short As[BM * BK];
    __shared__ __attribute__((aligned(16))) short Bs[BN * BK];

    const int tid  = threadIdx.x;
    const int wave = tid >> 6;
    const int lane = tid & 63;
    const int l15  = lane & 15;
    const int quad = lane >> 4;
    const int wm = wave >> 1, wn = wave & 1;
    const int n0 = blockIdx.x * BN;
    const int m0 = blockIdx.y * BM;

    f32x4 acc[WM / 16][WN / 16];
    #pragma unroll
    for (int i = 0; i < WM / 16; ++i)
        #pragma unroll
        for (int j = 0; j < WN / 16; ++j)
            acc[i][j] = (f32x4)0.0f;

    for (int k0 = 0; k0 < K; k0 += BK) {
        #pragma unroll
        for (int it = 0; it < BM / 64; ++it) {
            int e = (it * 256 + tid) * 8;
            int row = e >> 5, col = e & 31;
            gload16(As + (it * 256 + wave * 64) * 8,
                    A + (size_t)(m0 + row) * lda + k0 + col);
        }
        #pragma unroll
        for (int it = 0; it < BN / 64; ++it) {
            int e = (it * 256 + tid) * 8;
            int row = e >> 5, col = e & 31;
            gload16(Bs + (it * 256 + wave * 64) * 8,
                    Bt + (size_t)(n0 + row) * ldb + k0 + col);
        }
        __syncthreads();
        short8 af[WM / 16], bfr[WN / 16];
        #pragma unroll
        for (int i = 0; i < WM / 16; ++i)
            af[i] = *(const short8*)(As + (wm * WM + i * 16 + l15) * BK + quad * 8);
        #pragma unroll
        for (int j = 0; j < WN / 16; ++j)
            bfr[j] = *(const short8*)(Bs + (wn * WN + j * 16 + l15) * BK + quad * 8);
        #pragma unroll
        for (int i = 0; i < WM / 16; ++i)
            #pragma unroll
            for (int j = 0; j < WN / 16; ++j)
                acc[i][j] = mfma16(af[i], bfr[j], acc[i][j]);
        __syncthreads();
    }

    #pragma unroll
    for (int i = 0; i < WM / 16; ++i) {
        #pragma unroll
        for (int j = 0; j < WN / 16; ++j) {
            int row = m0 + wm * WM + i * 16 + quad * 4;
            int col = n0 + wn * WN + j * 16 + l15;
            float bia = bias ? bias[col] : 0.0f;
            #pragma unroll
            for (int r = 0; r < 4; ++r) {
                size_t off;
                if (REMAP == 1)
                    off = ((size_t)((row + r) & 63) * SS + ((row + r) >> 6)) * N + col;
                else if (REMAP == 2)
                    off = (((size_t)((row + r) & 63) * SS + ((row + r) >> 6)) * UU
                           + (col & 1023)) * 4 + (col >> 10);
                else
                    off = (size_t)(row + r) * N + col;
                float v = acc[i][j][r] + bia;
                if (OUT_BF16) ((short*)C)[off] = f2bf(v);
                else          ((float*)C)[off] = v;
            }
        }
    }
}

// ---------------------------------------------------------------------------
// Transpose fp32 [K][N] -> bf16 [N][K]
// ---------------------------------------------------------------------------
__global__ __launch_bounds__(256) void transpose_bf(
    const float* __restrict__ in, short* __restrict__ out, int ldin, int ldout)
{
    __shared__ float tile[64][65];
    int n0 = blockIdx.x * 64, k0 = blockIdx.y * 64;
    int c = threadIdx.x & 63, rr = threadIdx.x >> 6;
    #pragma unroll 4
    for (int i = 0; i < 16; ++i) {
        int row = rr * 16 + i;
        tile[row][c] = in[(size_t)(k0 + row) * ldin + n0 + c];
    }
    __syncthreads();
    #pragma unroll 4
    for (int i = 0; i < 16; ++i) {
        int row = rr * 16 + i;
        out[(size_t)(n0 + row) * ldout + k0 + c] = f2bf(tile[c][row]);
    }
}

// ---------------------------------------------------------------------------
// Fused transpose + MFMA-fragment pack: fp32 W[K][N] -> packed bf16
// Wp[((nt*(K/32)+it)*64+lane)*8+e] = bf16(W[it*32+(lane>>4)*8+e][nt*16+(lane&15)])
// Grid ((K/32)/4, N/16), 256 threads.
// ---------------------------------------------------------------------------
__global__ __launch_bounds__(256) void transpose_pack(
    const float* __restrict__ W, short* __restrict__ Wp, int N, int K)
{
    int lane = threadIdx.x & 63;
    int it = blockIdx.x * 4 + (threadIdx.x >> 6);
    int nt = blockIdx.y;
    int KI = K >> 5;
    int kb = it * 32 + (lane >> 4) * 8;
    int n  = nt * 16 + (lane & 15);
    short8 v;
    #pragma unroll
    for (int e = 0; e < 8; ++e)
        v[e] = f2bf(W[(size_t)(kb + e) * N + n]);
    *(short8*)(Wp + (((size_t)nt * KI + it) * 64 + lane) * 8) = v;
}

// ---------------------------------------------------------------------------
// Prep: gather embeddings, convert h0, zero pads/out/barriers.
// ---------------------------------------------------------------------------
__global__ __launch_bounds__(256) void prep_gather(
    const int* __restrict__ inp, const int* __restrict__ targ,
    const float* __restrict__ enc_emb, const float* __restrict__ dec_emb,
    const float* __restrict__ enc_h0,
    short* __restrict__ Ae, short* __restrict__ Ad,
    short* __restrict__ H_bf, short* __restrict__ h0_bf,
    float* __restrict__ out, int* __restrict__ bar)
{
    int blk = blockIdx.x, tid = threadIdx.x;
    if (blk < MPAD) {
        int s = blk >> 6, b = blk & 63;
        int row = inp[b * SS + s];
        Ae[(size_t)blk * EE + tid] = f2bf(enc_emb[(size_t)row * EE + tid]);
    } else if (blk < 2 * MPAD) {
        int m = blk - MPAD;
        if (m < TD * BB) {
            int t = m >> 6, b = m & 63;
            int row = targ[b * TT + t];
            Ad[(size_t)m * EE + tid] = f2bf(dec_emb[(size_t)row * EE + tid]);
        } else {
            Ad[(size_t)m * EE + tid] = 0;
        }
    } else {
        int r = blk - 2 * MPAD;  // 0..63
        for (int u = tid; u < UU; u += 256) {
            H_bf[(size_t)(TD * BB + r) * UU + u] = 0;   // fc pad rows
            h0_bf[(size_t)r * UU + u] = f2bf(enc_h0[(size_t)r * UU + u]);
        }
        if (r == 0) {
            bar[tid] = 0;                                // 256 barrier words
            if (tid == 0) out[0] = 0.0f;
        }
    }
}

// ---------------------------------------------------------------------------
// Encoder persistent scan (r4-proven). 64 blocks x 1024 threads. Block j owns
// u-cols [j*16,(j+1)*16). wave=(bg,kq). Weights L2-resident (packed).
// ---------------------------------------------------------------------------
__global__ __launch_bounds__(1024) void enc_scan(
    const short* __restrict__ h0, const short* __restrict__ Whp,
    const short* __restrict__ gi, const float* __restrict__ bias2,
    short* __restrict__ eout, int* __restrict__ bar)
{
    const int j    = blockIdx.x;
    const int tid  = threadIdx.x;
    const int lane = tid & 63;
    const int l15  = lane & 15;
    const int quad = lane >> 4;
    const int wave = tid >> 6;
    const int bg   = wave & 3;
    const int kq   = wave >> 2;
    const int u    = j * 16 + l15;

    __shared__ f32x4 red[4][3][4][64];   // [kq][gate][bg][lane]
    int* flags = bar;     int* go = bar + 64;

    const short* Bp0 = Whp + ((((size_t)(0 * 64 + j)) * 32 + kq * 8) * 64 + lane) * 8;
    const short* Bp1 = Whp + ((((size_t)(1 * 64 + j)) * 32 + kq * 8) * 64 + lane) * 8;
    const short* Bp2 = Whp + ((((size_t)(2 * 64 + j)) * 32 + kq * 8) * 64 + lane) * 8;
    const float bz = bias2[u], br = bias2[UU + u], bh = bias2[2 * UU + u];

    for (int t = 0; t < SS; ++t) {
        const short* A = t ? eout + (size_t)(t - 1) * BB * UU : h0;
        const short* Arow = A + (size_t)(bg * 16 + l15) * UU + kq * 256 + quad * 8;
        short8 af[8];
        #pragma unroll
        for (int i = 0; i < 8; ++i) af[i] = *(const short8*)(Arow + i * 32);
        f32x4 a0 = (f32x4)0.0f, a1 = (f32x4)0.0f, a2 = (f32x4)0.0f;
        #pragma unroll
        for (int i = 0; i < 8; ++i) {
            a0 = mfma16(af[i], *(const short8*)(Bp0 + i * 512), a0);
            a1 = mfma16(af[i], *(const short8*)(Bp1 + i * 512), a1);
            a2 = mfma16(af[i], *(const short8*)(Bp2 + i * 512), a2);
        }
        red[kq][0][bg][lane] = a0;
        red[kq][1][bg][lane] = a1;
        red[kq][2][bg][lane] = a2;
        __syncthreads();
        if (kq == 0) {
            f32x4 s0 = red[0][0][bg][lane] + red[1][0][bg][lane] + red[2][0][bg][lane] + red[3][0][bg][lane];
            f32x4 s1 = red[0][1][bg][lane] + red[1][1][bg][lane] + red[2][1][bg][lane] + red[3][1][bg][lane];
            f32x4 s2 = red[0][2][bg][lane] + red[1][2][bg][lane] + red[2][2][bg][lane] + red[3][2][bg][lane];
            const short* git = gi + (size_t)t * BB * G3;
            float hv[4];
            #pragma unroll
            for (int r = 0; r < 4; ++r) {
                int b = bg * 16 + quad * 4 + r;
                hv[r] = bf2f(A[(size_t)b * UU + u]);
            }
            #pragma unroll
            for (int r = 0; r < 4; ++r) {
                int b = bg * 16 + quad * 4 + r;
                const short* gb = git + (size_t)b * G3;
                float iz = bf2f(gb[u]), ir = bf2f(gb[UU + u]), ih = bf2f(gb[2 * UU + u]);
                float z  = sigm(iz + s0[r] + bz);
                float rr = sigm(ir + s1[r] + br);
                float hc = ftanh(ih + rr * (s2[r] + bh));
                vstore_bf(eout + (size_t)t * BB * UU + (size_t)b * UU + u,
                          z * hv[r] + (1.0f - z) * hc);
            }
        }
        if (t != SS - 1) gbar(flags, go, t + 1);
    }
}

// ---------------------------------------------------------------------------
// Decoder scan, BARRIER-FREE. 64 independent blocks x 512 threads (8 waves);
// block b owns batch row b end-to-end:
//   P1 : q = dh @ W1 + b1 computed LOCALLY via M=1 MFMA broadcast trick.
//        Each wave covers 8 u-tiles x full K (256 MFMAs), streaming the
//        shared fragment-packed W1p (2 MB, L2-resident per XCD). All 16
//        A-rows equal dh (l15 unused in the A-fragment), so C row 0 = dh.W1;
//        read at quad==0, reg 0 (C/D map: col=lane&15, row=(lane>>4)*4+reg).
//   P2 : scores (8-wave stride) + softmax, q from LDS.
//   P3 : ctx over Pp4 slice (u-split across 512 threads x 2) + GRU(h=0);
//        new dh -> LDS (and Hbf for the fc).
// No grid barriers, no volatile stores, plain (non-cooperative) launch.
// ---------------------------------------------------------------------------
__global__ __launch_bounds__(512) void dec_scan(
    const short* __restrict__ eout, const short* __restrict__ W1p,
    const float* __restrict__ b1, const short* __restrict__ keyp,
    const float* __restrict__ Vw, const float* __restrict__ bV,
    const short* __restrict__ Pp4, const short* __restrict__ xg,
    const float* __restrict__ db1, short* __restrict__ Hbf)
{
    const int b    = blockIdx.x;
    const int tid  = threadIdx.x;
    const int lane = tid & 63;
    const int l15  = lane & 15;
    const int quad = lane >> 4;
    const int wave = tid >> 6;          // 0..7

    __shared__ __attribute__((aligned(16))) short dh_lds[UU];
    __shared__ float q_lds[UU];
    __shared__ float sc[64];
    __shared__ float attnw[64];

    // initial dh = eout[SS-1][b] (written by enc_scan in a previous dispatch)
    dh_lds[tid]       = eout[(size_t)(SS - 1) * BB * UU + (size_t)b * UU + tid];
    dh_lds[tid + 512] = eout[(size_t)(SS - 1) * BB * UU + (size_t)b * UU + tid + 512];

    const float bV0 = bV[0];
    float Vl[16];
    #pragma unroll
    for (int e = 0; e < 16; e += 4)
        *(float4*)&Vl[e] = *(const float4*)(Vw + lane * 16 + e);

    // P3 per-thread constants: this thread handles u = tid and u = tid+512
    const float dz3a = db1[tid],        dr3a = db1[UU + tid],        dh3a = db1[2 * UU + tid];
    const float dz3b = db1[tid + 512],  dr3b = db1[UU + tid + 512],  dh3b = db1[2 * UU + tid + 512];
    const short* Pb = Pp4 + (size_t)b * SS * UU * 4;

    // P1 per-wave: u-tiles nt = wave*8 + d, d=0..7; tile stride = 32*64*8 shorts
    const short* Bw = W1p + (size_t)(wave * 8) * 16384 + (size_t)lane * 8;
    const int u0 = wave * 128 + l15;
    float b1v[8];
    #pragma unroll
    for (int d = 0; d < 8; ++d) b1v[d] = b1[u0 + d * 16];

    __syncthreads();

    for (int t = 0; t < TD; ++t) {
        // ---- P1: q = dh @ W1 + b1 (block-local, M=1 MFMA) ----
        {
            f32x4 acc[8];
            #pragma unroll
            for (int d = 0; d < 8; ++d) acc[d] = (f32x4)0.0f;
            #pragma unroll
            for (int it = 0; it < 32; ++it) {
                short8 af = *(const short8*)(dh_lds + it * 32 + quad * 8);
                #pragma unroll
                for (int d = 0; d < 8; ++d)
                    acc[d] = mfma16(af, *(const short8*)(Bw + d * 16384 + it * 512), acc[d]);
            }
            if (quad == 0) {            // C row 0: lanes 0..15, reg 0
                #pragma unroll
                for (int d = 0; d < 8; ++d)
                    q_lds[u0 + d * 16] = acc[d][0] + b1v[d];
            }
        }
        __syncthreads();
        // ---- P2a: scores ----
        {
            float ql[16];
            #pragma unroll
            for (int e = 0; e < 16; ++e) ql[e] = q_lds[lane * 16 + e];
            for (int s = wave; s < SS; s += 8) {
                const short* kp = keyp + ((size_t)b * SS + s) * UU + lane * 16;
                short8 k0 = *(const short8*)kp;
                short8 k1 = *(const short8*)(kp + 8);
                float p = 0.0f;
                #pragma unroll
                for (int e = 0; e < 8; ++e) p += Vl[e] * ftanh(ql[e] + bf2f(k0[e]));
                #pragma unroll
                for (int e = 0; e < 8; ++e) p += Vl[8 + e] * ftanh(ql[8 + e] + bf2f(k1[e]));
                #pragma unroll
                for (int off = 32; off; off >>= 1) p += __shfl_down(p, off);
                if (lane == 0) sc[s] = p + bV0;
            }
        }
        __syncthreads();
        // ---- P2b: softmax ----
        if (wave == 0) {
            float v = (lane < SS) ? sc[lane] : -1e30f;
            float m = v;
            #pragma unroll
            for (int off = 32; off; off >>= 1) m = fmaxf(m, __shfl_down(m, off));
            m = __shfl(m, 0);
            float e = (lane < SS) ? __expf(v - m) : 0.0f;
            float ss = e;
            #pragma unroll
            for (int off = 32; off; off >>= 1) ss += __shfl_down(ss, off);
            ss = __shfl(ss, 0);
            if (lane < SS) attnw[lane] = e / ss;
        }
        __syncthreads();
        // ---- P3: ctx + GRU(h=0), two u's per thread ----
        {
            const short* xb = xg + ((size_t)t * BB + b) * G3;
            float g0a = bf2f(xb[tid]);
            float g1a = bf2f(xb[UU + tid]);
            float g2a = bf2f(xb[2 * UU + tid]);
            float g0b = bf2f(xb[tid + 512]);
            float g1b = bf2f(xb[UU + tid + 512]);
            float g2b = bf2f(xb[2 * UU + tid + 512]);
            const short* Pua = Pb + (size_t)tid * 4;
            const short* Pub = Pb + (size_t)(tid + 512) * 4;
            #pragma unroll 5
            for (int s = 0; s < SS; ++s) {
                float w = attnw[s];
                short4v pa = *(const short4v*)(Pua + (size_t)s * UU * 4);
                short4v pb2 = *(const short4v*)(Pub + (size_t)s * UU * 4);
                g0a += w * bf2f(pa[0]);
                g1a += w * bf2f(pa[1]);
                g2a += w * bf2f(pa[2]);
                g0b += w * bf2f(pb2[0]);
                g1b += w * bf2f(pb2[1]);
                g2b += w * bf2f(pb2[2]);
            }
            float za  = sigm(g0a + dz3a);
            float ra  = sigm(g1a + dr3a);
            float hca = ftanh(g2a + ra * dh3a);
            float zb  = sigm(g0b + dz3b);
            float rb  = sigm(g1b + dr3b);
            float hcb = ftanh(g2b + rb * dh3b);
            short hba = f2bf((1.0f - za) * hca);
            short hbb = f2bf((1.0f - zb) * hcb);
            Hbf[((size_t)t * BB + b) * UU + tid]       = hba;
            Hbf[((size_t)t * BB + b) * UU + tid + 512] = hbb;
            dh_lds[tid]       = hba;
            dh_lds[tid + 512] = hbb;
        }
        __syncthreads();
    }
}

// ---------------------------------------------------------------------------
// Loss over one logits chunk.
// ---------------------------------------------------------------------------
__global__ __launch_bounds__(256) void loss_kernel(
    const float* __restrict__ logits, const int* __restrict__ targ,
    int rows0, float* __restrict__ out)
{
    int gr = rows0 + blockIdx.x;
    int t = gr >> 6;
    if (t >= TD) return;
    int b = gr & 63;
    const float* lp = logits + (size_t)blockIdx.x * VT;
    int tid = threadIdx.x;
    __shared__ float redm[4], reds[4];

    float m = -INFINITY;
    for (int v = tid; v < VT; v += 256) m = fmaxf(m, lp[v]);
    #pragma unroll
    for (int off = 32; off; off >>= 1) m = fmaxf(m, __shfl_down(m, off));
    if ((tid & 63) == 0) redm[tid >> 6] = m;
    __syncthreads();
    float mm = fmaxf(fmaxf(redm[0], redm[1]), fmaxf(redm[2], redm[3]));

    float ssum = 0.0f;
    for (int v = tid; v < VT; v += 256) ssum += expf(lp[v] - mm);
    #pragma unroll
    for (int off = 32; off; off >>= 1) ssum += __shfl_down(ssum, off);
    if ((tid & 63) == 0) reds[tid >> 6] = ssum;
    __syncthreads();
    if (tid == 0) {
        float tot = reds[0] + reds[1] + reds[2] + reds[3];
        int y = targ[b * TT + t + 1];
        float nll = mm + logf(tot) - lp[y];
        if (y != 0) atomicAdd(out, nll * (1.0f / (float)BB));
    }
}

// ---------------------------------------------------------------------------
extern "C" void kernel_launch(void* const* d_in, const int* in_sizes, int n_in,
                              void* d_out, int out_size, void* d_ws, size_t ws_size,
                              hipStream_t stream)
{
    (void)in_sizes; (void)n_in; (void)out_size;
    const int*   inp      = (const int*)  d_in[0];
    const int*   targ     = (const int*)  d_in[1];
    const float* enc_h0   = (const float*)d_in[2];
    const float* enc_emb  = (const float*)d_in[3];
    const float* enc_Wx   = (const float*)d_in[4];
    const float* enc_Wh   = (const float*)d_in[5];
    const float* enc_b    = (const float*)d_in[6];
    const float* W1       = (const float*)d_in[7];
    const float* b1       = (const float*)d_in[8];
    const float* W2       = (const float*)d_in[9];
    const float* b2       = (const float*)d_in[10];
    const float* Vw       = (const float*)d_in[11];
    const float* bV       = (const float*)d_in[12];
    const float* dec_emb  = (const float*)d_in[13];
    const float* dec_Wx   = (const float*)d_in[14];
    /* dec_Wh (d_in[15]) mathematically unused: decoder GRU gets h==0 */
    const float* dec_b    = (const float*)d_in[16];
    const float* fc_W     = (const float*)d_in[17];
    const float* fc_b     = (const float*)d_in[18];
    float* out = (float*)d_out;

    char* p = (char*)d_ws;
    auto alloc = [&](size_t bytes) {
        char* r = (char*)(((uintptr_t)p + 255) & ~(uintptr_t)255);
        p = r + bytes;
        return r;
    };
    short* encWxt  = (short*)alloc((size_t)G3 * EE * 2);
    short* W2t     = (short*)alloc((size_t)UU * UU * 2);
    short* dWxt_c  = (short*)alloc((size_t)G3 * UU * 2);
    short* dWxt_e  = (short*)alloc((size_t)G3 * EE * 2);
    short* fcWt    = (short*)alloc((size_t)VT * UU * 2);
    short* encWhp  = (short*)alloc((size_t)G3 * UU * 2);   // fragment-packed
    short* W1p     = (short*)alloc((size_t)UU * UU * 2);   // fragment-packed
    short* Ae      = (short*)alloc((size_t)MPAD * EE * 2);
    short* Ad      = (short*)alloc((size_t)MPAD * EE * 2);
    short* enc_gi  = (short*)alloc((size_t)MPAD * G3 * 2);
    short* xemb_gi = (short*)alloc((size_t)MPAD * G3 * 2);
    short* enc_out = (short*)alloc((size_t)MPAD * UU * 2);
    short* keyp    = (short*)alloc((size_t)MPAD * UU * 2);     // [b][s][u]
    short* Pp4     = (short*)alloc((size_t)MPAD * UU * 4 * 2); // [b][s][u][4]
    short* H_bf    = (short*)alloc((size_t)MPAD * UU * 2);
    short* h0_bf   = (short*)alloc((size_t)BB * UU * 2);
    int*   bar     = (int*)alloc(256 * 4);

    // fc logits chunk: as large as the remaining workspace allows (<=640 rows)
    size_t used = (size_t)(p - (char*)d_ws);
    size_t avail = (ws_size > used) ? ws_size - used : 0;
    int chunkRows = 640;
    while (chunkRows > 128 && (size_t)chunkRows * VT * 4 + 4096 > avail) chunkRows -= 128;
    float* logits = (float*)alloc((size_t)chunkRows * VT * 4);

    // --- one-time prep (parallel) ---
    transpose_bf<<<dim3(G3/64, EE/64), 256, 0, stream>>>(enc_Wx, encWxt, G3, EE);
    transpose_bf<<<dim3(UU/64, UU/64), 256, 0, stream>>>(W2, W2t, UU, UU);
    transpose_bf<<<dim3(G3/64, UU/64), 256, 0, stream>>>(dec_Wx, dWxt_c, G3, UU);
    transpose_bf<<<dim3(G3/64, EE/64), 256, 0, stream>>>(dec_Wx + (size_t)UU * G3, dWxt_e, G3, EE);
    transpose_bf<<<dim3(VT/64, UU/64), 256, 0, stream>>>(fc_W, fcWt, VT, UU);
    transpose_pack<<<dim3(8, G3/16), 256, 0, stream>>>(enc_Wh, encWhp, G3, UU);
    transpose_pack<<<dim3(8, UU/16), 256, 0, stream>>>(W1, W1p, UU, UU);
    prep_gather<<<2 * MPAD + 64, 256, 0, stream>>>(inp, targ, enc_emb, dec_emb, enc_h0,
                                                   Ae, Ad, H_bf, h0_bf, out, bar);

    gemm_bf16<128,128,64,64,true,0><<<dim3(G3/128, MPAD/128), 256, 0, stream>>>(
        Ae, encWxt, enc_b, enc_gi, G3, EE, EE, EE);
    gemm_bf16<128,128,64,64,true,0><<<dim3(G3/128, MPAD/128), 256, 0, stream>>>(
        Ad, dWxt_e, dec_b, xemb_gi, G3, EE, EE, EE);

    // --- encoder persistent scan (cooperative launch for co-residency) ---
    {
        const short* a0 = h0_bf; const short* a1 = encWhp; const short* a2 = enc_gi;
        const float* a3 = enc_b + G3; short* a4 = enc_out; int* a5 = bar;
        void* args[] = {&a0, &a1, &a2, &a3, &a4, &a5};
        hipLaunchCooperativeKernel((void*)enc_scan, dim3(64), dim3(1024), args, 0, stream);
    }

    // keys -> [b][s][u];  P = eout @ dWx_ctx -> [b][s][u][gate-pad4]
    gemm_bf16<128,128,64,64,true,1><<<dim3(UU/128, MPAD/128), 256, 0, stream>>>(
        enc_out, W2t, b2, keyp, UU, UU, UU, UU);
    gemm_bf16<128,128,64,64,true,2><<<dim3(G3/128, MPAD/128), 256, 0, stream>>>(
        enc_out, dWxt_c, nullptr, Pp4, G3, UU, UU, UU);

    // --- decoder scan: 64 independent blocks, plain launch, no barriers ---
    dec_scan<<<dim3(BB), dim3(512), 0, stream>>>(
        enc_out, W1p, b1, keyp, Vw, bV, Pp4, xemb_gi, dec_b + G3, H_bf);

    // --- fc + loss, dynamic chunks ---
    for (int rows0 = 0; rows0 < MPAD; rows0 += chunkRows) {
        int rows = MPAD - rows0; if (rows > chunkRows) rows = chunkRows;
        gemm_bf16<128,128,64,64,false,0><<<dim3(VT/128, rows/128), 256, 0, stream>>>(
            H_bf + (size_t)rows0 * UU, fcWt, fc_b, logits, VT, UU, UU, UU);
        loss_kernel<<<rows, 256, 0, stream>>>(logits, targ, rows0, out);
    }
}

// Round 10
// 2586.394 us; speedup vs baseline: 2.7802x; 2.7802x over previous
//
#include <hip/hip_runtime.h>
#include <cstdint>
#include <cstddef>

#define BB 64      // batch
#define SS 50      // src len
#define TT 50      // tgt len
#define TD 49      // decoder steps
#define UU 1024    // hidden
#define EE 256     // embed
#define VT 16000   // tgt vocab
#define G3 3072    // 3*U
#define MPAD 3200  // 50*64 padded row count

using short8 = __attribute__((ext_vector_type(8))) short;
using short4v = __attribute__((ext_vector_type(4))) short;
using uint4v = __attribute__((ext_vector_type(4))) unsigned int;
using f32x4  = __attribute__((ext_vector_type(4))) float;

__device__ __forceinline__ short f2bf(float f) {
    uint32_t u = __float_as_uint(f);
    uint32_t r = (u + 0x7fffu + ((u >> 16) & 1u)) >> 16;
    return (short)r;
}
__device__ __forceinline__ float bf2f(short s) {
    return __uint_as_float(((uint32_t)(uint16_t)s) << 16);
}
__device__ __forceinline__ float sigm(float x) { return 1.0f / (1.0f + __expf(-x)); }
__device__ __forceinline__ float ftanh(float x) {
    float xc = fminf(fmaxf(x, -8.0f), 8.0f);
    float e = __expf(2.0f * xc);
    return (e - 1.0f) / (e + 1.0f);
}

// Cross-block data protocol (single-writer, write-once-per-launch buffers):
//   WRITES : write-through (volatile 2B stores) -- no dirty lines in the
//            writer's non-snooped XCD L2.
//   READS  : plain cached loads. Safe: every exchanged address is virgin for
//            this launch when read (eout/Hbf/q_t time-indexed), so no L1/L2
//            stale copies can exist. Lines are MALL-fetched once per XCD.
__device__ __forceinline__ void vstore_bf(short* p, float v) { *(volatile short*)p = f2bf(v); }

// Leader-based grid barrier (r0-proven): per-block arrival flags (plain
// relaxed stores, no RMW), block 0 ballot-polls all 64 flags, releases via
// `go`. Exit compiler barrier stops load hoisting above the barrier.
__device__ __forceinline__ void gbar(int* flags, int* go, int t) {
    asm volatile("s_waitcnt vmcnt(0)" ::: "memory");   // my data stores drained
    __syncthreads();
    if (blockIdx.x == 0) {
        if (threadIdx.x < 64) {
            if (threadIdx.x == 0)
                __hip_atomic_store(&flags[0], t, __ATOMIC_RELAXED, __HIP_MEMORY_SCOPE_AGENT);
            int v;
            do {
                v = __hip_atomic_load(&flags[threadIdx.x], __ATOMIC_RELAXED, __HIP_MEMORY_SCOPE_AGENT);
            } while (__ballot(v >= t) != ~0ull);
            if (threadIdx.x == 0)
                __hip_atomic_store(go, t, __ATOMIC_RELAXED, __HIP_MEMORY_SCOPE_AGENT);
        }
    } else {
        if (threadIdx.x == 0) {
            __hip_atomic_store(&flags[blockIdx.x], t, __ATOMIC_RELAXED, __HIP_MEMORY_SCOPE_AGENT);
            while (__hip_atomic_load(go, __ATOMIC_RELAXED, __HIP_MEMORY_SCOPE_AGENT) < t)
                __builtin_amdgcn_s_sleep(1);
        }
    }
    __syncthreads();
    asm volatile("" ::: "memory");                     // no load hoisting above
}

typedef __attribute__((address_space(3))) void lds_vp;
typedef __attribute__((address_space(1))) void gl_vp;
__device__ __forceinline__ void gload16(void* lds, const void* g) {
    __builtin_amdgcn_global_load_lds((const gl_vp*)(uintptr_t)g,
                                     (lds_vp*)(uint32_t)(uintptr_t)lds,
                                     16, 0, 0);
}
__device__ __forceinline__ f32x4 mfma16(short8 a, short8 b, f32x4 c) {
    return __builtin_amdgcn_mfma_f32_16x16x32_bf16(a, b, c, 0, 0, 0);
}

// ---------------------------------------------------------------------------
// bf16 MFMA GEMM: C[m][n] = sum_k A[m][k]*Bt[n][k] (+bias)
// REMAP 0: row-major [M][N].
// REMAP 1: rows m=s*64+b remapped to [b][s][N]   (keys layout)
// REMAP 2: [b][s][u][gate-pad4]                  (P layout, N=3072)
// ---------------------------------------------------------------------------
template<int BM, int BN, int WM, int WN, bool OUT_BF16, int REMAP>
__global__ __launch_bounds__(256) void gemm_bf16(
    const short* __restrict__ A, const short* __restrict__ Bt,
    const float* __restrict__ bias, void* __restrict__ C, int N, int K,
    int lda, int ldb)
{
    constexpr int BK = 32;
    __shared__ __attribute__((aligned(16))) short As[BM * BK];
    __shared__ __attribute__((aligned(16))) short Bs[BN * BK];

    const int tid  = threadIdx.x;
    const int wave = tid >> 6;
    const int lane = tid & 63;
    const int l15  = lane & 15;
    const int quad = lane >> 4;
    const int wm = wave >> 1, wn = wave & 1;
    const int n0 = blockIdx.x * BN;
    const int m0 = blockIdx.y * BM;

    f32x4 acc[WM / 16][WN / 16];
    #pragma unroll
    for (int i = 0; i < WM / 16; ++i)
        #pragma unroll
        for (int j = 0; j < WN / 16; ++j)
            acc[i][j] = (f32x4)0.0f;

    for (int k0 = 0; k0 < K; k0 += BK) {
        #pragma unroll
        for (int it = 0; it < BM / 64; ++it) {
            int e = (it * 256 + tid) * 8;
            int row = e >> 5, col = e & 31;
            gload16(As + (it * 256 + wave * 64) * 8,
                    A + (size_t)(m0 + row) * lda + k0 + col);
        }
        #pragma unroll
        for (int it = 0; it < BN / 64; ++it) {
            int e = (it * 256 + tid) * 8;
            int row = e >> 5, col = e & 31;
            gload16(Bs + (it * 256 + wave * 64) * 8,
                    Bt + (size_t)(n0 + row) * ldb + k0 + col);
        }
        __syncthreads();
        short8 af[WM / 16], bfr[WN / 16];
        #pragma unroll
        for (int i = 0; i < WM / 16; ++i)
            af[i] = *(const short8*)(As + (wm * WM + i * 16 + l15) * BK + quad * 8);
        #pragma unroll
        for (int j = 0; j < WN / 16; ++j)
            bfr[j] = *(const short8*)(Bs + (wn * WN + j * 16 + l15) * BK + quad * 8);
        #pragma unroll
        for (int i = 0; i < WM / 16; ++i)
            #pragma unroll
            for (int j = 0; j < WN / 16; ++j)
                acc[i][j] = mfma16(af[i], bfr[j], acc[i][j]);
        __syncthreads();
    }

    #pragma unroll
    for (int i = 0; i < WM / 16; ++i) {
        #pragma unroll
        for (int j = 0; j < WN / 16; ++j) {
            int row = m0 + wm * WM + i * 16 + quad * 4;
            int col = n0 + wn * WN + j * 16 + l15;
            float bia = bias ? bias[col] : 0.0f;
            #pragma unroll
            for (int r = 0; r < 4; ++r) {
                size_t off;
                if (REMAP == 1)
                    off = ((size_t)((row + r) & 63) * SS + ((row + r) >> 6)) * N + col;
                else if (REMAP == 2)
                    off = (((size_t)((row + r) & 63) * SS + ((row + r) >> 6)) * UU
                           + (col & 1023)) * 4 + (col >> 10);
                else
                    off = (size_t)(row + r) * N + col;
                float v = acc[i][j][r] + bia;
                if (OUT_BF16) ((short*)C)[off] = f2bf(v);
                else          ((float*)C)[off] = v;
            }
        }
    }
}

// ---------------------------------------------------------------------------
// Transpose fp32 [K][N] -> bf16 [N][K]
// ---------------------------------------------------------------------------
__global__ __launch_bounds__(256) void transpose_bf(
    const float* __restrict__ in, short* __restrict__ out, int ldin, int ldout)
{
    __shared__ float tile[64][65];
    int n0 = blockIdx.x * 64, k0 = blockIdx.y * 64;
    int c = threadIdx.x & 63, rr = threadIdx.x >> 6;
    #pragma unroll 4
    for (int i = 0; i < 16; ++i) {
        int row = rr * 16 + i;
        tile[row][c] = in[(size_t)(k0 + row) * ldin + n0 + c];
    }
    __syncthreads();
    #pragma unroll 4
    for (int i = 0; i < 16; ++i) {
        int row = rr * 16 + i;
        out[(size_t)(n0 + row) * ldout + k0 + c] = f2bf(tile[c][row]);
    }
}

// ---------------------------------------------------------------------------
// Fused transpose + MFMA-fragment pack: fp32 W[K][N] -> packed bf16
// Wp[((nt*(K/32)+it)*64+lane)*8+e] = bf16(W[it*32+(lane>>4)*8+e][nt*16+(lane&15)])
// Grid ((K/32)/4, N/16), 256 threads.
// ---------------------------------------------------------------------------
__global__ __launch_bounds__(256) void transpose_pack(
    const float* __restrict__ W, short* __restrict__ Wp, int N, int K)
{
    int lane = threadIdx.x & 63;
    int it = blockIdx.x * 4 + (threadIdx.x >> 6);
    int nt = blockIdx.y;
    int KI = K >> 5;
    int kb = it * 32 + (lane >> 4) * 8;
    int n  = nt * 16 + (lane & 15);
    short8 v;
    #pragma unroll
    for (int e = 0; e < 8; ++e)
        v[e] = f2bf(W[(size_t)(kb + e) * N + n]);
    *(short8*)(Wp + (((size_t)nt * KI + it) * 64 + lane) * 8) = v;
}

// ---------------------------------------------------------------------------
// Prep: gather embeddings, convert h0, zero pads/out/barriers.
// ---------------------------------------------------------------------------
__global__ __launch_bounds__(256) void prep_gather(
    const int* __restrict__ inp, const int* __restrict__ targ,
    const float* __restrict__ enc_emb, const float* __restrict__ dec_emb,
    const float* __restrict__ enc_h0,
    short* __restrict__ Ae, short* __restrict__ Ad,
    short* __restrict__ H_bf, short* __restrict__ h0_bf,
    float* __restrict__ out, int* __restrict__ bar)
{
    int blk = blockIdx.x, tid = threadIdx.x;
    if (blk < MPAD) {
        int s = blk >> 6, b = blk & 63;
        int row = inp[b * SS + s];
        Ae[(size_t)blk * EE + tid] = f2bf(enc_emb[(size_t)row * EE + tid]);
    } else if (blk < 2 * MPAD) {
        int m = blk - MPAD;
        if (m < TD * BB) {
            int t = m >> 6, b = m & 63;
            int row = targ[b * TT + t];
            Ad[(size_t)m * EE + tid] = f2bf(dec_emb[(size_t)row * EE + tid]);
        } else {
            Ad[(size_t)m * EE + tid] = 0;
        }
    } else {
        int r = blk - 2 * MPAD;  // 0..63
        for (int u = tid; u < UU; u += 256) {
            H_bf[(size_t)(TD * BB + r) * UU + u] = 0;   // fc pad rows
            h0_bf[(size_t)r * UU + u] = f2bf(enc_h0[(size_t)r * UU + u]);
        }
        if (r == 0) {
            bar[tid] = 0;                                // 256 barrier words
            if (tid == 0) out[0] = 0.0f;
        }
    }
}

// ---------------------------------------------------------------------------
// Encoder persistent scan (r4-proven). 64 blocks x 1024 threads. Block j owns
// u-cols [j*16,(j+1)*16). wave=(bg,kq). Weights L2-resident (packed).
// Exchange reads are plain cached loads (virgin addresses, see protocol).
// ---------------------------------------------------------------------------
__global__ __launch_bounds__(1024) void enc_scan(
    const short* __restrict__ h0, const short* __restrict__ Whp,
    const short* __restrict__ gi, const float* __restrict__ bias2,
    short* __restrict__ eout, int* __restrict__ bar)
{
    const int j    = blockIdx.x;
    const int tid  = threadIdx.x;
    const int lane = tid & 63;
    const int l15  = lane & 15;
    const int quad = lane >> 4;
    const int wave = tid >> 6;
    const int bg   = wave & 3;
    const int kq   = wave >> 2;
    const int u    = j * 16 + l15;

    __shared__ f32x4 red[4][3][4][64];   // [kq][gate][bg][lane]
    int* flags = bar;     int* go = bar + 64;

    const short* Bp0 = Whp + ((((size_t)(0 * 64 + j)) * 32 + kq * 8) * 64 + lane) * 8;
    const short* Bp1 = Whp + ((((size_t)(1 * 64 + j)) * 32 + kq * 8) * 64 + lane) * 8;
    const short* Bp2 = Whp + ((((size_t)(2 * 64 + j)) * 32 + kq * 8) * 64 + lane) * 8;
    const float bz = bias2[u], br = bias2[UU + u], bh = bias2[2 * UU + u];

    for (int t = 0; t < SS; ++t) {
        const short* A = t ? eout + (size_t)(t - 1) * BB * UU : h0;
        const short* Arow = A + (size_t)(bg * 16 + l15) * UU + kq * 256 + quad * 8;
        short8 af[8];
        #pragma unroll
        for (int i = 0; i < 8; ++i) af[i] = *(const short8*)(Arow + i * 32);
        f32x4 a0 = (f32x4)0.0f, a1 = (f32x4)0.0f, a2 = (f32x4)0.0f;
        #pragma unroll
        for (int i = 0; i < 8; ++i) {
            a0 = mfma16(af[i], *(const short8*)(Bp0 + i * 512), a0);
            a1 = mfma16(af[i], *(const short8*)(Bp1 + i * 512), a1);
            a2 = mfma16(af[i], *(const short8*)(Bp2 + i * 512), a2);
        }
        red[kq][0][bg][lane] = a0;
        red[kq][1][bg][lane] = a1;
        red[kq][2][bg][lane] = a2;
        __syncthreads();
        if (kq == 0) {
            f32x4 s0 = red[0][0][bg][lane] + red[1][0][bg][lane] + red[2][0][bg][lane] + red[3][0][bg][lane];
            f32x4 s1 = red[0][1][bg][lane] + red[1][1][bg][lane] + red[2][1][bg][lane] + red[3][1][bg][lane];
            f32x4 s2 = red[0][2][bg][lane] + red[1][2][bg][lane] + red[2][2][bg][lane] + red[3][2][bg][lane];
            const short* git = gi + (size_t)t * BB * G3;
            float hv[4];
            #pragma unroll
            for (int r = 0; r < 4; ++r) {
                int b = bg * 16 + quad * 4 + r;
                hv[r] = bf2f(A[(size_t)b * UU + u]);
            }
            #pragma unroll
            for (int r = 0; r < 4; ++r) {
                int b = bg * 16 + quad * 4 + r;
                const short* gb = git + (size_t)b * G3;
                float iz = bf2f(gb[u]), ir = bf2f(gb[UU + u]), ih = bf2f(gb[2 * UU + u]);
                float z  = sigm(iz + s0[r] + bz);
                float rr = sigm(ir + s1[r] + br);
                float hc = ftanh(ih + rr * (s2[r] + bh));
                vstore_bf(eout + (size_t)t * BB * UU + (size_t)b * UU + u,
                          z * hv[r] + (1.0f - z) * hc);
            }
        }
        if (t != SS - 1) gbar(flags, go, t + 1);
    }
}

// ---------------------------------------------------------------------------
// Decoder persistent scan (r4 structure + LDS-resident per-block constants).
// 64 blocks x 1024 threads. 2 phases / 2 barriers per step:
//  P1 : block j computes q_t[t][all b][u-slice j] = dh @ W1 + b1 (k-split),
//       B-operands from the 32 KB W1p slice staged ONCE in LDS (Ws).
//  P23: block b: scores from the 100 KB keyp slice staged ONCE in LDS (Ks),
//       softmax, then ctx over Pp4 + GRU(h=0) -> Hbf[t][b].
// Staging removes the per-step L2 re-read of both constants (they previously
// contended with the Pp4 stream for the 4 MB per-XCD L2).
// ---------------------------------------------------------------------------
__global__ __launch_bounds__(1024) void dec_scan(
    const short* __restrict__ eout, const short* __restrict__ W1p,
    const float* __restrict__ b1, const short* __restrict__ keyp,
    const float* __restrict__ Vw, const float* __restrict__ bV,
    const short* __restrict__ Pp4, const short* __restrict__ xg,
    const float* __restrict__ db1, short* __restrict__ q_t,
    short* __restrict__ Hbf, int* __restrict__ bar)
{
    const int j    = blockIdx.x;
    const int tid  = threadIdx.x;
    const int lane = tid & 63;
    const int l15  = lane & 15;
    const int quad = lane >> 4;
    const int wave = tid >> 6;
    const int bg   = wave & 3;
    const int kq   = wave >> 2;
    const int u    = j * 16 + l15;

    __shared__ f32x4 redq[4][4][64];     // [kq][bg][lane], 16 KB
    __shared__ float sc[64];
    __shared__ float attnw[64];
    __shared__ __attribute__((aligned(16))) short Ws[32 * 512];   // 32 KB W1p slice
    __shared__ __attribute__((aligned(16))) short Ks[SS * UU];    // 100 KB keyp slice
    int* flags = bar + 128;  int* go = bar + 192;

    // ---- one-time staging of per-block constants into LDS ----
    {
        const short* wsrc = W1p + (size_t)j * 32 * 512;
        for (int c = wave; c < 32; c += 16)
            gload16(Ws + (size_t)c * 512, wsrc + ((size_t)c * 64 + lane) * 8);
        const short* ksrc = keyp + (size_t)j * SS * UU;
        for (int c = wave; c < (SS * UU) / 512; c += 16)      // 100 chunks x 1 KB
            gload16(Ks + (size_t)c * 512, ksrc + ((size_t)c * 64 + lane) * 8);
        asm volatile("s_waitcnt vmcnt(0)" ::: "memory");
        __syncthreads();
    }

    const short* BpQ = Ws + (size_t)kq * 4096 + (size_t)lane * 8;
    const float b1v = b1[u];
    const float bV0 = bV[0];

    float Vl[16];
    #pragma unroll
    for (int e = 0; e < 16; e += 4)
        *(float4*)&Vl[e] = *(const float4*)(Vw + lane * 16 + e);

    // P23 per-thread constants (u = tid)
    const float dz3 = db1[tid], dr3 = db1[UU + tid], dh3 = db1[2 * UU + tid];
    const short* Pb = Pp4 + (size_t)j * SS * UU * 4;   // block b = j slice

    for (int t = 0; t < TD; ++t) {
        const short* dh = t ? Hbf + (size_t)(t - 1) * BB * UU
                            : eout + (size_t)(SS - 1) * BB * UU;
        short* qt = q_t + (size_t)t * BB * UU;
        // ---- P1: q slice (block j), k-split over 16 waves, B from LDS ----
        {
            const short* Arow = dh + (size_t)(bg * 16 + l15) * UU + kq * 256 + quad * 8;
            short8 af[8];
            #pragma unroll
            for (int i = 0; i < 8; ++i) af[i] = *(const short8*)(Arow + i * 32);
            f32x4 aq = (f32x4)0.0f;
            #pragma unroll
            for (int i = 0; i < 8; ++i)
                aq = mfma16(af[i], *(const short8*)(BpQ + i * 512), aq);
            redq[kq][bg][lane] = aq;
        }
        __syncthreads();
        if (kq == 0) {
            f32x4 s = redq[0][bg][lane] + redq[1][bg][lane] + redq[2][bg][lane] + redq[3][bg][lane];
            #pragma unroll
            for (int r = 0; r < 4; ++r)
                vstore_bf(qt + (size_t)(bg * 16 + quad * 4 + r) * UU + u, s[r] + b1v);
        }
        gbar(flags, go, 2 * t + 1);
        // ---- P23: block = batch b = j ----
        {
            const int b = j;
            float ql[16];
            {
                short8 q0 = *(const short8*)(qt + (size_t)b * UU + lane * 16);
                short8 q1 = *(const short8*)(qt + (size_t)b * UU + lane * 16 + 8);
                #pragma unroll
                for (int e = 0; e < 8; ++e) { ql[e] = bf2f(q0[e]); ql[8 + e] = bf2f(q1[e]); }
            }
            for (int s = wave; s < SS; s += 16) {
                const short* kp = Ks + (size_t)s * UU + lane * 16;
                short8 k0 = *(const short8*)kp;
                short8 k1 = *(const short8*)(kp + 8);
                float p = 0.0f;
                #pragma unroll
                for (int e = 0; e < 8; ++e) p += Vl[e] * ftanh(ql[e] + bf2f(k0[e]));
                #pragma unroll
                for (int e = 0; e < 8; ++e) p += Vl[8 + e] * ftanh(ql[8 + e] + bf2f(k1[e]));
                #pragma unroll
                for (int off = 32; off; off >>= 1) p += __shfl_down(p, off);
                if (lane == 0) sc[s] = p + bV0;
            }
            __syncthreads();
            if (wave == 0) {
                float v = (lane < SS) ? sc[lane] : -1e30f;
                float m = v;
                #pragma unroll
                for (int off = 32; off; off >>= 1) m = fmaxf(m, __shfl_down(m, off));
                m = __shfl(m, 0);
                float e = (lane < SS) ? __expf(v - m) : 0.0f;
                float ss = e;
                #pragma unroll
                for (int off = 32; off; off >>= 1) ss += __shfl_down(ss, off);
                ss = __shfl(ss, 0);
                if (lane < SS) attnw[lane] = e / ss;
            }
            __syncthreads();
            // init gates from xemb, then ctx over contiguous cached Pp4 slice;
            // unroll 10 keeps 10 independent L2 loads in flight
            const short* xb = xg + ((size_t)t * BB + b) * G3;
            float g0 = bf2f(xb[tid]);
            float g1 = bf2f(xb[UU + tid]);
            float g2 = bf2f(xb[2 * UU + tid]);
            const short* Pu = Pb + (size_t)tid * 4;
            #pragma unroll 10
            for (int s = 0; s < SS; ++s) {
                float w = attnw[s];
                short4v pv = *(const short4v*)(Pu + (size_t)s * UU * 4);
                g0 += w * bf2f(pv[0]);
                g1 += w * bf2f(pv[1]);
                g2 += w * bf2f(pv[2]);
            }
            float z  = sigm(g0 + dz3);
            float rr = sigm(g1 + dr3);
            float hc = ftanh(g2 + rr * dh3);
            vstore_bf(Hbf + ((size_t)t * BB + b) * UU + tid, (1.0f - z) * hc);
        }
        if (t != TD - 1) gbar(flags, go, 2 * t + 2);
    }
}

// ---------------------------------------------------------------------------
// Loss over one logits chunk.
// ---------------------------------------------------------------------------
__global__ __launch_bounds__(256) void loss_kernel(
    const float* __restrict__ logits, const int* __restrict__ targ,
    int rows0, float* __restrict__ out)
{
    int gr = rows0 + blockIdx.x;
    int t = gr >> 6;
    if (t >= TD) return;
    int b = gr & 63;
    const float* lp = logits + (size_t)blockIdx.x * VT;
    int tid = threadIdx.x;
    __shared__ float redm[4], reds[4];

    float m = -INFINITY;
    for (int v = tid; v < VT; v += 256) m = fmaxf(m, lp[v]);
    #pragma unroll
    for (int off = 32; off; off >>= 1) m = fmaxf(m, __shfl_down(m, off));
    if ((tid & 63) == 0) redm[tid >> 6] = m;
    __syncthreads();
    float mm = fmaxf(fmaxf(redm[0], redm[1]), fmaxf(redm[2], redm[3]));

    float ssum = 0.0f;
    for (int v = tid; v < VT; v += 256) ssum += expf(lp[v] - mm);
    #pragma unroll
    for (int off = 32; off; off >>= 1) ssum += __shfl_down(ssum, off);
    if ((tid & 63) == 0) reds[tid >> 6] = ssum;
    __syncthreads();
    if (tid == 0) {
        float tot = reds[0] + reds[1] + reds[2] + reds[3];
        int y = targ[b * TT + t + 1];
        float nll = mm + logf(tot) - lp[y];
        if (y != 0) atomicAdd(out, nll * (1.0f / (float)BB));
    }
}

// ---------------------------------------------------------------------------
extern "C" void kernel_launch(void* const* d_in, const int* in_sizes, int n_in,
                              void* d_out, int out_size, void* d_ws, size_t ws_size,
                              hipStream_t stream)
{
    (void)in_sizes; (void)n_in; (void)out_size;
    const int*   inp      = (const int*)  d_in[0];
    const int*   targ     = (const int*)  d_in[1];
    const float* enc_h0   = (const float*)d_in[2];
    const float* enc_emb  = (const float*)d_in[3];
    const float* enc_Wx   = (const float*)d_in[4];
    const float* enc_Wh   = (const float*)d_in[5];
    const float* enc_b    = (const float*)d_in[6];
    const float* W1       = (const float*)d_in[7];
    const float* b1       = (const float*)d_in[8];
    const float* W2       = (const float*)d_in[9];
    const float* b2       = (const float*)d_in[10];
    const float* Vw       = (const float*)d_in[11];
    const float* bV       = (const float*)d_in[12];
    const float* dec_emb  = (const float*)d_in[13];
    const float* dec_Wx   = (const float*)d_in[14];
    /* dec_Wh (d_in[15]) mathematically unused: decoder GRU gets h==0 */
    const float* dec_b    = (const float*)d_in[16];
    const float* fc_W     = (const float*)d_in[17];
    const float* fc_b     = (const float*)d_in[18];
    float* out = (float*)d_out;

    char* p = (char*)d_ws;
    auto alloc = [&](size_t bytes) {
        char* r = (char*)(((uintptr_t)p + 255) & ~(uintptr_t)255);
        p = r + bytes;
        return r;
    };
    short* encWxt  = (short*)alloc((size_t)G3 * EE * 2);
    short* W2t     = (short*)alloc((size_t)UU * UU * 2);
    short* dWxt_c  = (short*)alloc((size_t)G3 * UU * 2);
    short* dWxt_e  = (short*)alloc((size_t)G3 * EE * 2);
    short* fcWt    = (short*)alloc((size_t)VT * UU * 2);
    short* encWhp  = (short*)alloc((size_t)G3 * UU * 2);   // fragment-packed
    short* W1p     = (short*)alloc((size_t)UU * UU * 2);   // fragment-packed
    short* Ae      = (short*)alloc((size_t)MPAD * EE * 2);
    short* Ad      = (short*)alloc((size_t)MPAD * EE * 2);
    short* enc_gi  = (short*)alloc((size_t)MPAD * G3 * 2);
    short* xemb_gi = (short*)alloc((size_t)MPAD * G3 * 2);
    short* enc_out = (short*)alloc((size_t)MPAD * UU * 2);
    short* keyp    = (short*)alloc((size_t)MPAD * UU * 2);     // [b][s][u]
    short* Pp4     = (short*)alloc((size_t)MPAD * UU * 4 * 2); // [b][s][u][4]
    short* H_bf    = (short*)alloc((size_t)MPAD * UU * 2);
    short* h0_bf   = (short*)alloc((size_t)BB * UU * 2);
    short* q_t     = (short*)alloc((size_t)TD * BB * UU * 2);  // time-indexed q
    int*   bar     = (int*)alloc(256 * 4);

    // fc logits chunk: as large as the remaining workspace allows (<=640 rows)
    size_t used = (size_t)(p - (char*)d_ws);
    size_t avail = (ws_size > used) ? ws_size - used : 0;
    int chunkRows = 640;
    while (chunkRows > 128 && (size_t)chunkRows * VT * 4 + 4096 > avail) chunkRows -= 128;
    float* logits = (float*)alloc((size_t)chunkRows * VT * 4);

    // --- one-time prep (parallel) ---
    transpose_bf<<<dim3(G3/64, EE/64), 256, 0, stream>>>(enc_Wx, encWxt, G3, EE);
    transpose_bf<<<dim3(UU/64, UU/64), 256, 0, stream>>>(W2, W2t, UU, UU);
    transpose_bf<<<dim3(G3/64, UU/64), 256, 0, stream>>>(dec_Wx, dWxt_c, G3, UU);
    transpose_bf<<<dim3(G3/64, EE/64), 256, 0, stream>>>(dec_Wx + (size_t)UU * G3, dWxt_e, G3, EE);
    transpose_bf<<<dim3(VT/64, UU/64), 256, 0, stream>>>(fc_W, fcWt, VT, UU);
    transpose_pack<<<dim3(8, G3/16), 256, 0, stream>>>(enc_Wh, encWhp, G3, UU);
    transpose_pack<<<dim3(8, UU/16), 256, 0, stream>>>(W1, W1p, UU, UU);
    prep_gather<<<2 * MPAD + 64, 256, 0, stream>>>(inp, targ, enc_emb, dec_emb, enc_h0,
                                                   Ae, Ad, H_bf, h0_bf, out, bar);

    gemm_bf16<128,128,64,64,true,0><<<dim3(G3/128, MPAD/128), 256, 0, stream>>>(
        Ae, encWxt, enc_b, enc_gi, G3, EE, EE, EE);
    gemm_bf16<128,128,64,64,true,0><<<dim3(G3/128, MPAD/128), 256, 0, stream>>>(
        Ad, dWxt_e, dec_b, xemb_gi, G3, EE, EE, EE);

    // --- encoder persistent scan (cooperative launch for co-residency) ---
    {
        const short* a0 = h0_bf; const short* a1 = encWhp; const short* a2 = enc_gi;
        const float* a3 = enc_b + G3; short* a4 = enc_out; int* a5 = bar;
        void* args[] = {&a0, &a1, &a2, &a3, &a4, &a5};
        hipLaunchCooperativeKernel((void*)enc_scan, dim3(64), dim3(1024), args, 0, stream);
    }

    // keys -> [b][s][u];  P = eout @ dWx_ctx -> [b][s][u][gate-pad4]
    gemm_bf16<128,128,64,64,true,1><<<dim3(UU/128, MPAD/128), 256, 0, stream>>>(
        enc_out, W2t, b2, keyp, UU, UU, UU, UU);
    gemm_bf16<128,128,64,64,true,2><<<dim3(G3/128, MPAD/128), 256, 0, stream>>>(
        enc_out, dWxt_c, nullptr, Pp4, G3, UU, UU, UU);

    // --- decoder persistent scan (cooperative) ---
    {
        const short* a0 = enc_out; const short* a1 = W1p; const float* a2 = b1;
        const short* a3 = keyp; const float* a4 = Vw; const float* a5 = bV;
        const short* a6 = Pp4; const short* a7 = xemb_gi; const float* a8 = dec_b + G3;
        short* a9 = q_t; short* a10 = H_bf; int* a11 = bar;
        void* args[] = {&a0, &a1, &a2, &a3, &a4, &a5, &a6, &a7, &a8, &a9, &a10, &a11};
        hipLaunchCooperativeKernel((void*)dec_scan, dim3(64), dim3(1024), args, 0, stream);
    }

    // --- fc + loss, dynamic chunks ---
    for (int rows0 = 0; rows0 < MPAD; rows0 += chunkRows) {
        int rows = MPAD - rows0; if (rows > chunkRows) rows = chunkRows;
        gemm_bf16<128,128,64,64,false,0><<<dim3(VT/128, rows/128), 256, 0, stream>>>(
            H_bf + (size_t)rows0 * UU, fcWt, fc_b, logits, VT, UU, UU, UU);
        loss_kernel<<<rows, 256, 0, stream>>>(logits, targ, rows0, out);
    }
}

// Round 11
// 2342.620 us; speedup vs baseline: 3.0695x; 1.1041x over previous
//
#include <hip/hip_runtime.h>
#include <cstdint>
#include <cstddef>

#define BB 64      // batch
#define SS 50      // src len
#define TT 50      // tgt len
#define TD 49      // decoder steps
#define UU 1024    // hidden
#define EE 256     // embed
#define VT 16000   // tgt vocab
#define G3 3072    // 3*U
#define MPAD 3200  // 50*64 padded row count
#define NCT 125    // fc col-tiles (16000/128)

using short8 = __attribute__((ext_vector_type(8))) short;
using short4v = __attribute__((ext_vector_type(4))) short;
using uint4v = __attribute__((ext_vector_type(4))) unsigned int;
using f32x4  = __attribute__((ext_vector_type(4))) float;

__device__ __forceinline__ short f2bf(float f) {
    uint32_t u = __float_as_uint(f);
    uint32_t r = (u + 0x7fffu + ((u >> 16) & 1u)) >> 16;
    return (short)r;
}
__device__ __forceinline__ float bf2f(short s) {
    return __uint_as_float(((uint32_t)(uint16_t)s) << 16);
}
__device__ __forceinline__ float sigm(float x) { return 1.0f / (1.0f + __expf(-x)); }
__device__ __forceinline__ float ftanh(float x) {
    float xc = fminf(fmaxf(x, -8.0f), 8.0f);
    float e = __expf(2.0f * xc);
    return (e - 1.0f) / (e + 1.0f);
}
// dynamic f32x4 element select without scratch (rule #20): cndmask chain
__device__ __forceinline__ float vsel(f32x4 v, int k) {
    return (k == 0) ? v[0] : (k == 1) ? v[1] : (k == 2) ? v[2] : v[3];
}

// Cross-block data protocol (single-writer, write-once-per-launch buffers):
//   WRITES : write-through (volatile 2B stores).
//   READS  : plain cached loads on virgin (time-indexed) addresses.
__device__ __forceinline__ void vstore_bf(short* p, float v) { *(volatile short*)p = f2bf(v); }

// Leader-based grid barrier (r0-proven).
__device__ __forceinline__ void gbar(int* flags, int* go, int t) {
    asm volatile("s_waitcnt vmcnt(0)" ::: "memory");   // my data stores drained
    __syncthreads();
    if (blockIdx.x == 0) {
        if (threadIdx.x < 64) {
            if (threadIdx.x == 0)
                __hip_atomic_store(&flags[0], t, __ATOMIC_RELAXED, __HIP_MEMORY_SCOPE_AGENT);
            int v;
            do {
                v = __hip_atomic_load(&flags[threadIdx.x], __ATOMIC_RELAXED, __HIP_MEMORY_SCOPE_AGENT);
            } while (__ballot(v >= t) != ~0ull);
            if (threadIdx.x == 0)
                __hip_atomic_store(go, t, __ATOMIC_RELAXED, __HIP_MEMORY_SCOPE_AGENT);
        }
    } else {
        if (threadIdx.x == 0) {
            __hip_atomic_store(&flags[blockIdx.x], t, __ATOMIC_RELAXED, __HIP_MEMORY_SCOPE_AGENT);
            while (__hip_atomic_load(go, __ATOMIC_RELAXED, __HIP_MEMORY_SCOPE_AGENT) < t)
                __builtin_amdgcn_s_sleep(1);
        }
    }
    __syncthreads();
    asm volatile("" ::: "memory");                     // no load hoisting above
}

typedef __attribute__((address_space(3))) void lds_vp;
typedef __attribute__((address_space(1))) void gl_vp;
__device__ __forceinline__ void gload16(void* lds, const void* g) {
    __builtin_amdgcn_global_load_lds((const gl_vp*)(uintptr_t)g,
                                     (lds_vp*)(uint32_t)(uintptr_t)lds,
                                     16, 0, 0);
}
__device__ __forceinline__ f32x4 mfma16(short8 a, short8 b, f32x4 c) {
    return __builtin_amdgcn_mfma_f32_16x16x32_bf16(a, b, c, 0, 0, 0);
}

// ---------------------------------------------------------------------------
// bf16 MFMA GEMM: C[m][n] = sum_k A[m][k]*Bt[n][k] (+bias)
// REMAP 0: row-major [M][N].
// REMAP 1: rows m=s*64+b remapped to [b][s][N]   (keys layout)
// REMAP 2: [b][s][u][gate-pad4]                  (P layout, N=3072)
// ---------------------------------------------------------------------------
template<int BM, int BN, int WM, int WN, bool OUT_BF16, int REMAP>
__global__ __launch_bounds__(256) void gemm_bf16(
    const short* __restrict__ A, const short* __restrict__ Bt,
    const float* __restrict__ bias, void* __restrict__ C, int N, int K,
    int lda, int ldb)
{
    constexpr int BK = 32;
    __shared__ __attribute__((aligned(16))) short As[BM * BK];
    __shared__ __attribute__((aligned(16))) short Bs[BN * BK];

    const int tid  = threadIdx.x;
    const int wave = tid >> 6;
    const int lane = tid & 63;
    const int l15  = lane & 15;
    const int quad = lane >> 4;
    const int wm = wave >> 1, wn = wave & 1;
    const int n0 = blockIdx.x * BN;
    const int m0 = blockIdx.y * BM;

    f32x4 acc[WM / 16][WN / 16];
    #pragma unroll
    for (int i = 0; i < WM / 16; ++i)
        #pragma unroll
        for (int j = 0; j < WN / 16; ++j)
            acc[i][j] = (f32x4)0.0f;

    for (int k0 = 0; k0 < K; k0 += BK) {
        #pragma unroll
        for (int it = 0; it < BM / 64; ++it) {
            int e = (it * 256 + tid) * 8;
            int row = e >> 5, col = e & 31;
            gload16(As + (it * 256 + wave * 64) * 8,
                    A + (size_t)(m0 + row) * lda + k0 + col);
        }
        #pragma unroll
        for (int it = 0; it < BN / 64; ++it) {
            int e = (it * 256 + tid) * 8;
            int row = e >> 5, col = e & 31;
            gload16(Bs + (it * 256 + wave * 64) * 8,
                    Bt + (size_t)(n0 + row) * ldb + k0 + col);
        }
        __syncthreads();
        short8 af[WM / 16], bfr[WN / 16];
        #pragma unroll
        for (int i = 0; i < WM / 16; ++i)
            af[i] = *(const short8*)(As + (wm * WM + i * 16 + l15) * BK + quad * 8);
        #pragma unroll
        for (int j = 0; j < WN / 16; ++j)
            bfr[j] = *(const short8*)(Bs + (wn * WN + j * 16 + l15) * BK + quad * 8);
        #pragma unroll
        for (int i = 0; i < WM / 16; ++i)
            #pragma unroll
            for (int j = 0; j < WN / 16; ++j)
                acc[i][j] = mfma16(af[i], bfr[j], acc[i][j]);
        __syncthreads();
    }

    #pragma unroll
    for (int i = 0; i < WM / 16; ++i) {
        #pragma unroll
        for (int j = 0; j < WN / 16; ++j) {
            int row = m0 + wm * WM + i * 16 + quad * 4;
            int col = n0 + wn * WN + j * 16 + l15;
            float bia = bias ? bias[col] : 0.0f;
            #pragma unroll
            for (int r = 0; r < 4; ++r) {
                size_t off;
                if (REMAP == 1)
                    off = ((size_t)((row + r) & 63) * SS + ((row + r) >> 6)) * N + col;
                else if (REMAP == 2)
                    off = (((size_t)((row + r) & 63) * SS + ((row + r) >> 6)) * UU
                           + (col & 1023)) * 4 + (col >> 10);
                else
                    off = (size_t)(row + r) * N + col;
                float v = acc[i][j][r] + bia;
                if (OUT_BF16) ((short*)C)[off] = f2bf(v);
                else          ((float*)C)[off] = v;
            }
        }
    }
}

// ---------------------------------------------------------------------------
// fc GEMM with fused online-softmax stats. Each block computes a 128x128
// logits tile from H_bf @ fcWt + fc_b, but instead of writing 64 KB of
// logits it writes per-row {tile-max, tile-sumexp} (exact rescaled-sum
// representation) and extracts the target-class logit. Replaces the
// 200 MB logits round-trip + chunked loss kernels.
// Grid (125, 25), 256 threads.
// ---------------------------------------------------------------------------
__global__ __launch_bounds__(256) void fc_gemm(
    const short* __restrict__ A, const short* __restrict__ Bt,
    const float* __restrict__ bias, const int* __restrict__ targ,
    float2* __restrict__ stats, float* __restrict__ tgtlog)
{
    constexpr int BM = 128, BN = 128, BK = 32;
    __shared__ __attribute__((aligned(16))) short As[BM * BK];
    __shared__ __attribute__((aligned(16))) short Bs[BN * BK];
    __shared__ float2 st[BM][2];

    const int tid  = threadIdx.x;
    const int wave = tid >> 6;
    const int lane = tid & 63;
    const int l15  = lane & 15;
    const int quad = lane >> 4;
    const int wm = wave >> 1, wn = wave & 1;
    const int n0 = blockIdx.x * BN;
    const int m0 = blockIdx.y * BM;

    f32x4 acc[4][4];
    #pragma unroll
    for (int i = 0; i < 4; ++i)
        #pragma unroll
        for (int j = 0; j < 4; ++j)
            acc[i][j] = (f32x4)0.0f;

    for (int k0 = 0; k0 < UU; k0 += BK) {
        #pragma unroll
        for (int it = 0; it < 2; ++it) {
            int e = (it * 256 + tid) * 8;
            int row = e >> 5, col = e & 31;
            gload16(As + (it * 256 + wave * 64) * 8,
                    A + (size_t)(m0 + row) * UU + k0 + col);
            gload16(Bs + (it * 256 + wave * 64) * 8,
                    Bt + (size_t)(n0 + row) * UU + k0 + col);
        }
        __syncthreads();
        short8 af[4], bfr[4];
        #pragma unroll
        for (int i = 0; i < 4; ++i)
            af[i] = *(const short8*)(As + (wm * 64 + i * 16 + l15) * BK + quad * 8);
        #pragma unroll
        for (int j = 0; j < 4; ++j)
            bfr[j] = *(const short8*)(Bs + (wn * 64 + j * 16 + l15) * BK + quad * 8);
        #pragma unroll
        for (int i = 0; i < 4; ++i)
            #pragma unroll
            for (int j = 0; j < 4; ++j)
                acc[i][j] = mfma16(af[i], bfr[j], acc[i][j]);
        __syncthreads();
    }

    float bia[4];
    #pragma unroll
    for (int j = 0; j < 4; ++j)
        bia[j] = bias[n0 + wn * 64 + j * 16 + l15];

    #pragma unroll
    for (int i = 0; i < 4; ++i) {
        #pragma unroll
        for (int r = 0; r < 4; ++r) {
            float v0 = acc[i][0][r] + bia[0];
            float v1 = acc[i][1][r] + bia[1];
            float v2 = acc[i][2][r] + bia[2];
            float v3 = acc[i][3][r] + bia[3];
            float mx = fmaxf(fmaxf(v0, v1), fmaxf(v2, v3));
            #pragma unroll
            for (int off = 1; off < 16; off <<= 1)
                mx = fmaxf(mx, __shfl_xor(mx, off));
            float se = __expf(v0 - mx) + __expf(v1 - mx)
                     + __expf(v2 - mx) + __expf(v3 - mx);
            #pragma unroll
            for (int off = 1; off < 16; off <<= 1)
                se += __shfl_xor(se, off);
            int rowt = wm * 64 + i * 16 + quad * 4 + r;
            if (l15 == 0) st[rowt][wn] = make_float2(mx, se);
            // target-class logit extraction (one writer per valid row)
            int grow = m0 + rowt;
            int tt = grow >> 6, bb = grow & 63;
            if (tt < TD) {
                int y = targ[bb * TT + tt + 1];
                int yl = y - n0;
                if (yl >= 0 && yl < BN && (yl >> 6) == wn && (yl & 15) == l15) {
                    int jy = (yl >> 4) & 3;
                    float tv = (jy == 0) ? v0 : (jy == 1) ? v1 : (jy == 2) ? v2 : v3;
                    tgtlog[grow] = tv;
                }
            }
        }
    }
    __syncthreads();
    if (tid < BM) {
        float2 a2 = st[tid][0], b2 = st[tid][1];
        float M = fmaxf(a2.x, b2.x);
        float S = a2.y * __expf(a2.x - M) + b2.y * __expf(b2.x - M);
        stats[(size_t)(m0 + tid) * NCT + blockIdx.x] = make_float2(M, S);
    }
}

// ---------------------------------------------------------------------------
// Combine per-tile stats into the final NLL sum. One 64-thread block per
// valid row (TD*BB blocks); 125 contiguous float2 reads per row.
// ---------------------------------------------------------------------------
__global__ __launch_bounds__(64) void loss_combine(
    const float2* __restrict__ stats, const float* __restrict__ tgtlog,
    const int* __restrict__ targ, float* __restrict__ out)
{
    int grow = blockIdx.x;              // < TD*BB
    int tid = threadIdx.x;              // 0..63
    const float2* sp = stats + (size_t)grow * NCT;
    float2 e0 = sp[tid];
    float M = e0.x, S = e0.y;
    if (tid + 64 < NCT) {
        float2 e1 = sp[tid + 64];
        float Mn = fmaxf(M, e1.x);
        S = S * __expf(M - Mn) + e1.y * __expf(e1.x - Mn);
        M = Mn;
    }
    #pragma unroll
    for (int off = 32; off; off >>= 1) {
        float Mo = __shfl_down(M, off);
        float So = __shfl_down(S, off);
        float Mn = fmaxf(M, Mo);
        S = S * __expf(M - Mn) + So * __expf(Mo - Mn);
        M = Mn;
    }
    if (tid == 0) {
        int tt = grow >> 6, bb = grow & 63;
        int y = targ[bb * TT + tt + 1];
        float nll = M + logf(S) - tgtlog[grow];
        if (y != 0) atomicAdd(out, nll * (1.0f / (float)BB));
    }
}

// ---------------------------------------------------------------------------
// Transpose fp32 [K][N] -> bf16 [N][K]
// ---------------------------------------------------------------------------
__global__ __launch_bounds__(256) void transpose_bf(
    const float* __restrict__ in, short* __restrict__ out, int ldin, int ldout)
{
    __shared__ float tile[64][65];
    int n0 = blockIdx.x * 64, k0 = blockIdx.y * 64;
    int c = threadIdx.x & 63, rr = threadIdx.x >> 6;
    #pragma unroll 4
    for (int i = 0; i < 16; ++i) {
        int row = rr * 16 + i;
        tile[row][c] = in[(size_t)(k0 + row) * ldin + n0 + c];
    }
    __syncthreads();
    #pragma unroll 4
    for (int i = 0; i < 16; ++i) {
        int row = rr * 16 + i;
        out[(size_t)(n0 + row) * ldout + k0 + c] = f2bf(tile[c][row]);
    }
}

// ---------------------------------------------------------------------------
// Fused transpose + MFMA-fragment pack: fp32 W[K][N] -> packed bf16
// ---------------------------------------------------------------------------
__global__ __launch_bounds__(256) void transpose_pack(
    const float* __restrict__ W, short* __restrict__ Wp, int N, int K)
{
    int lane = threadIdx.x & 63;
    int it = blockIdx.x * 4 + (threadIdx.x >> 6);
    int nt = blockIdx.y;
    int KI = K >> 5;
    int kb = it * 32 + (lane >> 4) * 8;
    int n  = nt * 16 + (lane & 15);
    short8 v;
    #pragma unroll
    for (int e = 0; e < 8; ++e)
        v[e] = f2bf(W[(size_t)(kb + e) * N + n]);
    *(short8*)(Wp + (((size_t)nt * KI + it) * 64 + lane) * 8) = v;
}

// ---------------------------------------------------------------------------
// Prep: gather embeddings, convert h0, zero pads/out/barriers.
// ---------------------------------------------------------------------------
__global__ __launch_bounds__(256) void prep_gather(
    const int* __restrict__ inp, const int* __restrict__ targ,
    const float* __restrict__ enc_emb, const float* __restrict__ dec_emb,
    const float* __restrict__ enc_h0,
    short* __restrict__ Ae, short* __restrict__ Ad,
    short* __restrict__ H_bf, short* __restrict__ h0_bf,
    float* __restrict__ out, int* __restrict__ bar)
{
    int blk = blockIdx.x, tid = threadIdx.x;
    if (blk < MPAD) {
        int s = blk >> 6, b = blk & 63;
        int row = inp[b * SS + s];
        Ae[(size_t)blk * EE + tid] = f2bf(enc_emb[(size_t)row * EE + tid]);
    } else if (blk < 2 * MPAD) {
        int m = blk - MPAD;
        if (m < TD * BB) {
            int t = m >> 6, b = m & 63;
            int row = targ[b * TT + t];
            Ad[(size_t)m * EE + tid] = f2bf(dec_emb[(size_t)row * EE + tid]);
        } else {
            Ad[(size_t)m * EE + tid] = 0;
        }
    } else {
        int r = blk - 2 * MPAD;  // 0..63
        for (int u = tid; u < UU; u += 256) {
            H_bf[(size_t)(TD * BB + r) * UU + u] = 0;   // fc pad rows
            h0_bf[(size_t)r * UU + u] = f2bf(enc_h0[(size_t)r * UU + u]);
        }
        if (r == 0) {
            bar[tid] = 0;                                // 256 barrier words
            if (tid == 0) out[0] = 0.0f;
        }
    }
}

// ---------------------------------------------------------------------------
// Encoder persistent scan (r4 structure; GRU tail spread across ALL 16
// waves: wave kq handles r=kq, cutting the tail's serial latency 4x).
// ---------------------------------------------------------------------------
__global__ __launch_bounds__(1024) void enc_scan(
    const short* __restrict__ h0, const short* __restrict__ Whp,
    const short* __restrict__ gi, const float* __restrict__ bias2,
    short* __restrict__ eout, int* __restrict__ bar)
{
    const int j    = blockIdx.x;
    const int tid  = threadIdx.x;
    const int lane = tid & 63;
    const int l15  = lane & 15;
    const int quad = lane >> 4;
    const int wave = tid >> 6;
    const int bg   = wave & 3;
    const int kq   = wave >> 2;
    const int u    = j * 16 + l15;

    __shared__ f32x4 red[4][3][4][64];   // [kq][gate][bg][lane]
    int* flags = bar;     int* go = bar + 64;

    const short* Bp0 = Whp + ((((size_t)(0 * 64 + j)) * 32 + kq * 8) * 64 + lane) * 8;
    const short* Bp1 = Whp + ((((size_t)(1 * 64 + j)) * 32 + kq * 8) * 64 + lane) * 8;
    const short* Bp2 = Whp + ((((size_t)(2 * 64 + j)) * 32 + kq * 8) * 64 + lane) * 8;
    const float bz = bias2[u], br = bias2[UU + u], bh = bias2[2 * UU + u];

    for (int t = 0; t < SS; ++t) {
        const short* A = t ? eout + (size_t)(t - 1) * BB * UU : h0;
        const short* Arow = A + (size_t)(bg * 16 + l15) * UU + kq * 256 + quad * 8;
        short8 af[8];
        #pragma unroll
        for (int i = 0; i < 8; ++i) af[i] = *(const short8*)(Arow + i * 32);
        f32x4 a0 = (f32x4)0.0f, a1 = (f32x4)0.0f, a2 = (f32x4)0.0f;
        #pragma unroll
        for (int i = 0; i < 8; ++i) {
            a0 = mfma16(af[i], *(const short8*)(Bp0 + i * 512), a0);
            a1 = mfma16(af[i], *(const short8*)(Bp1 + i * 512), a1);
            a2 = mfma16(af[i], *(const short8*)(Bp2 + i * 512), a2);
        }
        red[kq][0][bg][lane] = a0;
        red[kq][1][bg][lane] = a1;
        red[kq][2][bg][lane] = a2;
        __syncthreads();
        {
            f32x4 s0 = red[0][0][bg][lane] + red[1][0][bg][lane] + red[2][0][bg][lane] + red[3][0][bg][lane];
            f32x4 s1 = red[0][1][bg][lane] + red[1][1][bg][lane] + red[2][1][bg][lane] + red[3][1][bg][lane];
            f32x4 s2 = red[0][2][bg][lane] + red[1][2][bg][lane] + red[2][2][bg][lane] + red[3][2][bg][lane];
            const int r = kq;                        // wave kq owns residual r
            const int b = bg * 16 + quad * 4 + r;
            float s0v = vsel(s0, r), s1v = vsel(s1, r), s2v = vsel(s2, r);
            float hv = bf2f(A[(size_t)b * UU + u]);
            const short* gb = gi + (size_t)t * BB * G3 + (size_t)b * G3;
            float iz = bf2f(gb[u]), ir = bf2f(gb[UU + u]), ih = bf2f(gb[2 * UU + u]);
            float z  = sigm(iz + s0v + bz);
            float rr = sigm(ir + s1v + br);
            float hc = ftanh(ih + rr * (s2v + bh));
            vstore_bf(eout + (size_t)t * BB * UU + (size_t)b * UU + u,
                      z * hv + (1.0f - z) * hc);
        }
        if (t != SS - 1) gbar(flags, go, t + 1);
    }
}

// ---------------------------------------------------------------------------
// Decoder persistent scan (r10 structure: LDS-resident W1p/keyp slices;
// q-write spread across all 16 waves: wave kq stores element r=kq).
// ---------------------------------------------------------------------------
__global__ __launch_bounds__(1024) void dec_scan(
    const short* __restrict__ eout, const short* __restrict__ W1p,
    const float* __restrict__ b1, const short* __restrict__ keyp,
    const float* __restrict__ Vw, const float* __restrict__ bV,
    const short* __restrict__ Pp4, const short* __restrict__ xg,
    const float* __restrict__ db1, short* __restrict__ q_t,
    short* __restrict__ Hbf, int* __restrict__ bar)
{
    const int j    = blockIdx.x;
    const int tid  = threadIdx.x;
    const int lane = tid & 63;
    const int l15  = lane & 15;
    const int quad = lane >> 4;
    const int wave = tid >> 6;
    const int bg   = wave & 3;
    const int kq   = wave >> 2;
    const int u    = j * 16 + l15;

    __shared__ f32x4 redq[4][4][64];     // [kq][bg][lane], 16 KB
    __shared__ float sc[64];
    __shared__ float attnw[64];
    __shared__ __attribute__((aligned(16))) short Ws[32 * 512];   // 32 KB W1p slice
    __shared__ __attribute__((aligned(16))) short Ks[SS * UU];    // 100 KB keyp slice
    int* flags = bar + 128;  int* go = bar + 192;

    // ---- one-time staging of per-block constants into LDS ----
    {
        const short* wsrc = W1p + (size_t)j * 32 * 512;
        for (int c = wave; c < 32; c += 16)
            gload16(Ws + (size_t)c * 512, wsrc + ((size_t)c * 64 + lane) * 8);
        const short* ksrc = keyp + (size_t)j * SS * UU;
        for (int c = wave; c < (SS * UU) / 512; c += 16)      // 100 chunks x 1 KB
            gload16(Ks + (size_t)c * 512, ksrc + ((size_t)c * 64 + lane) * 8);
        asm volatile("s_waitcnt vmcnt(0)" ::: "memory");
        __syncthreads();
    }

    const short* BpQ = Ws + (size_t)kq * 4096 + (size_t)lane * 8;
    const float b1v = b1[u];
    const float bV0 = bV[0];

    float Vl[16];
    #pragma unroll
    for (int e = 0; e < 16; e += 4)
        *(float4*)&Vl[e] = *(const float4*)(Vw + lane * 16 + e);

    // P23 per-thread constants (u = tid)
    const float dz3 = db1[tid], dr3 = db1[UU + tid], dh3 = db1[2 * UU + tid];
    const short* Pb = Pp4 + (size_t)j * SS * UU * 4;   // block b = j slice

    for (int t = 0; t < TD; ++t) {
        const short* dh = t ? Hbf + (size_t)(t - 1) * BB * UU
                            : eout + (size_t)(SS - 1) * BB * UU;
        short* qt = q_t + (size_t)t * BB * UU;
        // ---- P1: q slice (block j), k-split over 16 waves, B from LDS ----
        {
            const short* Arow = dh + (size_t)(bg * 16 + l15) * UU + kq * 256 + quad * 8;
            short8 af[8];
            #pragma unroll
            for (int i = 0; i < 8; ++i) af[i] = *(const short8*)(Arow + i * 32);
            f32x4 aq = (f32x4)0.0f;
            #pragma unroll
            for (int i = 0; i < 8; ++i)
                aq = mfma16(af[i], *(const short8*)(BpQ + i * 512), aq);
            redq[kq][bg][lane] = aq;
        }
        __syncthreads();
        {
            f32x4 s = redq[0][bg][lane] + redq[1][bg][lane] + redq[2][bg][lane] + redq[3][bg][lane];
            float sv = vsel(s, kq);                  // wave kq stores r=kq
            vstore_bf(qt + (size_t)(bg * 16 + quad * 4 + kq) * UU + u, sv + b1v);
        }
        gbar(flags, go, 2 * t + 1);
        // ---- P23: block = batch b = j ----
        {
            const int b = j;
            float ql[16];
            {
                short8 q0 = *(const short8*)(qt + (size_t)b * UU + lane * 16);
                short8 q1 = *(const short8*)(qt + (size_t)b * UU + lane * 16 + 8);
                #pragma unroll
                for (int e = 0; e < 8; ++e) { ql[e] = bf2f(q0[e]); ql[8 + e] = bf2f(q1[e]); }
            }
            for (int s = wave; s < SS; s += 16) {
                const short* kp = Ks + (size_t)s * UU + lane * 16;
                short8 k0 = *(const short8*)kp;
                short8 k1 = *(const short8*)(kp + 8);
                float p = 0.0f;
                #pragma unroll
                for (int e = 0; e < 8; ++e) p += Vl[e] * ftanh(ql[e] + bf2f(k0[e]));
                #pragma unroll
                for (int e = 0; e < 8; ++e) p += Vl[8 + e] * ftanh(ql[8 + e] + bf2f(k1[e]));
                #pragma unroll
                for (int off = 32; off; off >>= 1) p += __shfl_down(p, off);
                if (lane == 0) sc[s] = p + bV0;
            }
            __syncthreads();
            if (wave == 0) {
                float v = (lane < SS) ? sc[lane] : -1e30f;
                float m = v;
                #pragma unroll
                for (int off = 32; off; off >>= 1) m = fmaxf(m, __shfl_down(m, off));
                m = __shfl(m, 0);
                float e = (lane < SS) ? __expf(v - m) : 0.0f;
                float ss = e;
                #pragma unroll
                for (int off = 32; off; off >>= 1) ss += __shfl_down(ss, off);
                ss = __shfl(ss, 0);
                if (lane < SS) attnw[lane] = e / ss;
            }
            __syncthreads();
            // init gates from xemb, then ctx over contiguous cached Pp4 slice;
            // unroll 10 keeps 10 independent L2 loads in flight
            const short* xb = xg + ((size_t)t * BB + b) * G3;
            float g0 = bf2f(xb[tid]);
            float g1 = bf2f(xb[UU + tid]);
            float g2 = bf2f(xb[2 * UU + tid]);
            const short* Pu = Pb + (size_t)tid * 4;
            #pragma unroll 10
            for (int s = 0; s < SS; ++s) {
                float w = attnw[s];
                short4v pv = *(const short4v*)(Pu + (size_t)s * UU * 4);
                g0 += w * bf2f(pv[0]);
                g1 += w * bf2f(pv[1]);
                g2 += w * bf2f(pv[2]);
            }
            float z  = sigm(g0 + dz3);
            float rr = sigm(g1 + dr3);
            float hc = ftanh(g2 + rr * dh3);
            vstore_bf(Hbf + ((size_t)t * BB + b) * UU + tid, (1.0f - z) * hc);
        }
        if (t != TD - 1) gbar(flags, go, 2 * t + 2);
    }
}

// ---------------------------------------------------------------------------
extern "C" void kernel_launch(void* const* d_in, const int* in_sizes, int n_in,
                              void* d_out, int out_size, void* d_ws, size_t ws_size,
                              hipStream_t stream)
{
    (void)in_sizes; (void)n_in; (void)out_size; (void)ws_size;
    const int*   inp      = (const int*)  d_in[0];
    const int*   targ     = (const int*)  d_in[1];
    const float* enc_h0   = (const float*)d_in[2];
    const float* enc_emb  = (const float*)d_in[3];
    const float* enc_Wx   = (const float*)d_in[4];
    const float* enc_Wh   = (const float*)d_in[5];
    const float* enc_b    = (const float*)d_in[6];
    const float* W1       = (const float*)d_in[7];
    const float* b1       = (const float*)d_in[8];
    const float* W2       = (const float*)d_in[9];
    const float* b2       = (const float*)d_in[10];
    const float* Vw       = (const float*)d_in[11];
    const float* bV       = (const float*)d_in[12];
    const float* dec_emb  = (const float*)d_in[13];
    const float* dec_Wx   = (const float*)d_in[14];
    /* dec_Wh (d_in[15]) mathematically unused: decoder GRU gets h==0 */
    const float* dec_b    = (const float*)d_in[16];
    const float* fc_W     = (const float*)d_in[17];
    const float* fc_b     = (const float*)d_in[18];
    float* out = (float*)d_out;

    char* p = (char*)d_ws;
    auto alloc = [&](size_t bytes) {
        char* r = (char*)(((uintptr_t)p + 255) & ~(uintptr_t)255);
        p = r + bytes;
        return r;
    };
    short* encWxt  = (short*)alloc((size_t)G3 * EE * 2);
    short* W2t     = (short*)alloc((size_t)UU * UU * 2);
    short* dWxt_c  = (short*)alloc((size_t)G3 * UU * 2);
    short* dWxt_e  = (short*)alloc((size_t)G3 * EE * 2);
    short* fcWt    = (short*)alloc((size_t)VT * UU * 2);
    short* encWhp  = (short*)alloc((size_t)G3 * UU * 2);   // fragment-packed
    short* W1p     = (short*)alloc((size_t)UU * UU * 2);   // fragment-packed
    short* Ae      = (short*)alloc((size_t)MPAD * EE * 2);
    short* Ad      = (short*)alloc((size_t)MPAD * EE * 2);
    short* enc_gi  = (short*)alloc((size_t)MPAD * G3 * 2);
    short* xemb_gi = (short*)alloc((size_t)MPAD * G3 * 2);
    short* enc_out = (short*)alloc((size_t)MPAD * UU * 2);
    short* keyp    = (short*)alloc((size_t)MPAD * UU * 2);     // [b][s][u]
    short* Pp4     = (short*)alloc((size_t)MPAD * UU * 4 * 2); // [b][s][u][4]
    short* H_bf    = (short*)alloc((size_t)MPAD * UU * 2);
    short* h0_bf   = (short*)alloc((size_t)BB * UU * 2);
    short* q_t     = (short*)alloc((size_t)TD * BB * UU * 2);  // time-indexed q
    int*   bar     = (int*)alloc(256 * 4);
    float2* stats  = (float2*)alloc((size_t)MPAD * NCT * sizeof(float2));
    float* tgtlog  = (float*)alloc((size_t)MPAD * 4);

    // --- one-time prep (parallel) ---
    transpose_bf<<<dim3(G3/64, EE/64), 256, 0, stream>>>(enc_Wx, encWxt, G3, EE);
    transpose_bf<<<dim3(UU/64, UU/64), 256, 0, stream>>>(W2, W2t, UU, UU);
    transpose_bf<<<dim3(G3/64, UU/64), 256, 0, stream>>>(dec_Wx, dWxt_c, G3, UU);
    transpose_bf<<<dim3(G3/64, EE/64), 256, 0, stream>>>(dec_Wx + (size_t)UU * G3, dWxt_e, G3, EE);
    transpose_bf<<<dim3(VT/64, UU/64), 256, 0, stream>>>(fc_W, fcWt, VT, UU);
    transpose_pack<<<dim3(8, G3/16), 256, 0, stream>>>(enc_Wh, encWhp, G3, UU);
    transpose_pack<<<dim3(8, UU/16), 256, 0, stream>>>(W1, W1p, UU, UU);
    prep_gather<<<2 * MPAD + 64, 256, 0, stream>>>(inp, targ, enc_emb, dec_emb, enc_h0,
                                                   Ae, Ad, H_bf, h0_bf, out, bar);

    gemm_bf16<128,128,64,64,true,0><<<dim3(G3/128, MPAD/128), 256, 0, stream>>>(
        Ae, encWxt, enc_b, enc_gi, G3, EE, EE, EE);
    gemm_bf16<128,128,64,64,true,0><<<dim3(G3/128, MPAD/128), 256, 0, stream>>>(
        Ad, dWxt_e, dec_b, xemb_gi, G3, EE, EE, EE);

    // --- encoder persistent scan (cooperative launch for co-residency) ---
    {
        const short* a0 = h0_bf; const short* a1 = encWhp; const short* a2 = enc_gi;
        const float* a3 = enc_b + G3; short* a4 = enc_out; int* a5 = bar;
        void* args[] = {&a0, &a1, &a2, &a3, &a4, &a5};
        hipLaunchCooperativeKernel((void*)enc_scan, dim3(64), dim3(1024), args, 0, stream);
    }

    // keys -> [b][s][u];  P = eout @ dWx_ctx -> [b][s][u][gate-pad4]
    gemm_bf16<128,128,64,64,true,1><<<dim3(UU/128, MPAD/128), 256, 0, stream>>>(
        enc_out, W2t, b2, keyp, UU, UU, UU, UU);
    gemm_bf16<128,128,64,64,true,2><<<dim3(G3/128, MPAD/128), 256, 0, stream>>>(
        enc_out, dWxt_c, nullptr, Pp4, G3, UU, UU, UU);

    // --- decoder persistent scan (cooperative) ---
    {
        const short* a0 = enc_out; const short* a1 = W1p; const float* a2 = b1;
        const short* a3 = keyp; const float* a4 = Vw; const float* a5 = bV;
        const short* a6 = Pp4; const short* a7 = xemb_gi; const float* a8 = dec_b + G3;
        short* a9 = q_t; short* a10 = H_bf; int* a11 = bar;
        void* args[] = {&a0, &a1, &a2, &a3, &a4, &a5, &a6, &a7, &a8, &a9, &a10, &a11};
        hipLaunchCooperativeKernel((void*)dec_scan, dim3(64), dim3(1024), args, 0, stream);
    }

    // --- fused fc + loss: stats GEMM then single combine pass ---
    fc_gemm<<<dim3(VT/128, MPAD/128), 256, 0, stream>>>(
        H_bf, fcWt, fc_b, targ, stats, tgtlog);
    loss_combine<<<TD * BB, 64, 0, stream>>>(stats, tgtlog, targ, out);
}